// Round 12
// baseline (271.771 us; speedup 1.0000x reference)
//
#include <hip/hip_runtime.h>
#include <math.h>

#define TOK   16384
#define DIM   48
#define EMB   256
#define MF    128
#define IMGsz 129

typedef __attribute__((ext_vector_type(8))) short    bf16x8;
typedef __attribute__((ext_vector_type(8))) unsigned short u16x8;
typedef __attribute__((ext_vector_type(4))) unsigned short u16x4;
typedef __attribute__((ext_vector_type(4))) float    f32x4;

__device__ __forceinline__ ushort f2bf(float f) {
    union { float f; unsigned u; } v; v.f = f;
    unsigned u = v.u;
    return (ushort)((u + 0x7fffu + ((u >> 16) & 1u)) >> 16);   // RNE
}
__device__ __forceinline__ float bf2f(ushort h) {
    union { unsigned u; float f; } v; v.u = ((unsigned)h) << 16; return v.f;
}

// swizzles: XOR 16B-chunk index with (row&7) -> conflict-free ds_read_b128
#define SWZ64(r,c)  ((r)*64  + (((((c)>>3) ^ ((r)&7)) & 7) << 3) + ((c)&7))
#define SWZ256(r,c) ((r)*256 + (((((c)>>3) ^ ((r)&7))) << 3) + ((c)&7))

// fragment-major dst index for B operands: lane(l4,l15) of (ntile,kc) is contiguous.
__device__ __forceinline__ int fragmajor(int n, int k, int KC) {
    return (((n >> 4)*KC + (k >> 5))*4 + ((k >> 3) & 3))*128 + (n & 15)*8 + (k & 7);
}

// ---------------- kprep: fused weight build (fragment-major bf16) ----------------
// Wbig[640 cols][64 k]: 0..255 Wv | 256..383 Wk@Pt | 384..511 Wq@Pt
//                      | 512..575 Gk_aug | 576..639 Gq_aug  (h[48]=1 trick)
__global__ __launch_bounds__(256) void kprep(
    const float* __restrict__ w_kqv, const float* __restrict__ b_kqv,
    const float* __restrict__ w_prm,
    const float* __restrict__ w_mlp1, const float* __restrict__ w_mlp2,
    ushort* __restrict__ Wbig, ushort* __restrict__ wT2, float* __restrict__ bkq)
{
    __shared__ float redp[64][4];
    int blk = blockIdx.x, tid = threadIdx.x;
    if (blk < 256) {                       // v weights
        if (tid < 64) {
            float v = (tid < DIM) ? w_kqv[tid*768 + 512 + blk] : 0.f;
            Wbig[fragmajor(blk, tid, 2)] = f2bf(v);
        }
    } else if (blk < 512) {                // fused kp/qp logit weights: Wk@P^T
        int isQ = (blk >= 384);
        int m = blk - (isQ ? 384 : 256);
        int d = tid & 63, part = tid >> 6;
        float s = 0.f;
        if (d < 48) {
            const float* wr = w_kqv + d*768 + (isQ ? 256 : 0);
            const float* pr = w_prm + m*256;
            for (int n = part*64; n < part*64 + 64; n++) s += wr[n]*pr[n];
        }
        redp[d][part] = s;
        __syncthreads();
        if (tid < 64)
            Wbig[fragmajor((isQ ? 384 : 256) + m, tid, 2)] =
                f2bf(redp[tid][0]+redp[tid][1]+redp[tid][2]+redp[tid][3]);
    } else if (blk < 640) {                // G_aug quadratic-form weights
        int isQ = (blk >= 576);
        int j = blk - (isQ ? 576 : 512);
        int i = tid & 63, part = tid >> 6;
        int off = isQ ? 256 : 0;
        float s = 0.f;
        for (int n = part*64; n < part*64 + 64; n++) {
            float wi = (i < 48) ? w_kqv[i*768 + off + n] : (i == 48 ? b_kqv[off + n] : 0.f);
            float wj = (j < 48) ? w_kqv[j*768 + off + n] : (j == 48 ? b_kqv[off + n] : 0.f);
            s += wi*wj;
        }
        redp[i][part] = s;
        __syncthreads();
        if (tid < 64)
            Wbig[fragmajor((isQ ? 576 : 512) + j, tid, 2)] =
                f2bf(redp[tid][0]+redp[tid][1]+redp[tid][2]+redp[tid][3]);
    } else if (blk < 1152) {               // mlp weights fragment-major
        int w = (blk >= 896);
        int n = blk - (w ? 896 : 640);
        const float* src = w ? w_mlp2 : w_mlp1;
        wT2[w*65536 + fragmajor(n, tid, 8)] = f2bf(src[tid*256 + n]);
    } else {                               // performer feature biases P@b
        float s = 0.f;
        int m = tid & 127, off = (tid >= 128) ? 256 : 0;
        for (int n = 0; n < 256; n++) s += w_prm[m*256 + n]*b_kqv[off + n];
        bkq[tid] = s;
    }
}

// ---------------- kernel 1: unfold+LN+fused single GEMM (N=640, K=64) ------------
__global__ __launch_bounds__(256, 3) void k1_mfma(
    const float* __restrict__ x, const float* __restrict__ g1, const float* __restrict__ b1,
    const ushort* __restrict__ Wbig, const float* __restrict__ b_kqv,
    const float* __restrict__ bkq,
    ushort* __restrict__ vfrag_out, ushort* __restrict__ kpT_out, ushort* __restrict__ qp_out)
{
    __shared__ __align__(16) ushort h_bf[32*64];     // 4 KB swizzled (aug col 48 = 1.0)
    __shared__ __align__(16) ushort vt_bf[32*256];   // 16 KB: v staging
    __shared__ __align__(16) ushort kp_s[32*128];    // 8 KB
    __shared__ __align__(16) ushort qp_s[32*128];    // 8 KB
    __shared__ float xdp[4][32][2];
    __shared__ float red1[32][8], red2[32][8];
    __shared__ float mu_s[32], iv_s[32];
    float* t_s = (float*)vt_bf;                      // [32][48] unfold overlay

    const int blk = blockIdx.x;                      // 2048
    const int b  = blk >> 9;
    const int t0 = (blk & 511) << 5;
    const int tid = threadIdx.x;
    const int wid = tid >> 6;
    const int l15 = tid & 15, l4 = (tid >> 4) & 3;

    // ---- unfold 32 tokens x 48 ----
    for (int e = tid; e < 32*DIM; e += 256) {
        int tok = e / DIM, j = e - tok*DIM;
        int t = t0 + tok;
        int lh = t >> 7, lw = t & 127;
        int c = j >> 4, kh = (j >> 2) & 3, kw = j & 3;
        int ih = lh + kh - 1, iw = lw + kw - 1;
        float val = 0.f;
        if (ih >= 0 && ih < IMGsz && iw >= 0 && iw < IMGsz)
            val = x[((b*3 + c)*IMGsz + ih)*IMGsz + iw];
        t_s[tok*DIM + j] = val;
    }
    __syncthreads();

    // ---- LayerNorm -> h_bf (swizzled), aug col 48 = 1.0 ----
    {
        int tg = tid >> 3, sl = tid & 7;
        const float* tr = &t_s[tg*DIM + sl*6];
        float s1 = 0.f, s2 = 0.f;
        #pragma unroll
        for (int j = 0; j < 6; j++) { float a = tr[j]; s1 += a; s2 = fmaf(a, a, s2); }
        red1[tg][sl] = s1; red2[tg][sl] = s2;
        __syncthreads();
        if (tid < 32) {
            float a = 0.f, q = 0.f;
            #pragma unroll
            for (int j = 0; j < 8; j++) { a += red1[tid][j]; q += red2[tid][j]; }
            float mu = a * (1.f/DIM);
            mu_s[tid] = mu;
            iv_s[tid] = rsqrtf(q*(1.f/DIM) - mu*mu + 1e-5f);
        }
        __syncthreads();
        float mu = mu_s[tg], iv = iv_s[tg];
        float hv[6];
        #pragma unroll
        for (int j = 0; j < 6; j++) hv[j] = (tr[j]-mu)*iv;
        #pragma unroll
        for (int j = 0; j < 6; j++) {
            int c = sl*6 + j;
            h_bf[SWZ64(tg, c)] = f2bf(hv[j]*g1[c] + b1[c]);
        }
        int c0 = 48 + sl*2;
        h_bf[SWZ64(tg, c0    )] = (sl == 0) ? (ushort)0x3F80 : (ushort)0;  // h[48]=1.0
        h_bf[SWZ64(tg, c0 + 1)] = 0;
    }
    __syncthreads();

    // ---- single GEMM: 40 tiles strided across 4 waves (10 tiles/wave) ----
    f32x4 acc[10][2];
    #pragma unroll
    for (int j = 0; j < 10; j++)
        #pragma unroll
        for (int m = 0; m < 2; m++) { acc[j][m][0]=0.f; acc[j][m][1]=0.f; acc[j][m][2]=0.f; acc[j][m][3]=0.f; }
    #pragma unroll
    for (int kc = 0; kc < 2; kc++) {
        int ch = ((kc*4 + l4) ^ (l15 & 7)) << 3;
        bf16x8 a0 = *(const bf16x8*)&h_bf[ l15      *64 + ch];
        bf16x8 a1 = *(const bf16x8*)&h_bf[(16 + l15)*64 + ch];
        #pragma unroll
        for (int j = 0; j < 10; j++) {
            int tile = wid + 4*j;
            bf16x8 bb = *(const bf16x8*)&Wbig[(((tile*2 + kc)*4 + l4)*16 + l15)*8];
            acc[j][0] = __builtin_amdgcn_mfma_f32_16x16x32_bf16(a0, bb, acc[j][0], 0, 0, 0);
            acc[j][1] = __builtin_amdgcn_mfma_f32_16x16x32_bf16(a1, bb, acc[j][1], 0, 0, 0);
        }
    }

    // ---- v epilogue (tiles 0..15): + bias -> vt_bf ----
    #pragma unroll
    for (int j = 0; j < 4; j++) {
        int col = (wid + 4*j)*16 + l15;
        float bias = b_kqv[512 + col];
        #pragma unroll
        for (int m = 0; m < 2; m++)
            #pragma unroll
            for (int r = 0; r < 4; r++) {
                int row = m*16 + l4*4 + r;
                vt_bf[row*256 + col] = f2bf(acc[j][m][r] + bias);
            }
    }
    // ---- u epilogue (tiles 32..39): xd = 0.5 * h G h^T partials -> xdp ----
    #pragma unroll
    for (int m = 0; m < 2; m++)
        #pragma unroll
        for (int r = 0; r < 4; r++) {
            int row = m*16 + l4*4 + r;
            float hv = bf2f(h_bf[SWZ64(row, wid*16 + l15)]);
            float sk = acc[8][m][r]*hv, sq = acc[9][m][r]*hv;
            #pragma unroll
            for (int msk = 8; msk >= 1; msk >>= 1) {
                sk += __shfl_xor(sk, msk);
                sq += __shfl_xor(sq, msk);
            }
            if (l15 == 0) { xdp[wid][row][0] = sk; xdp[wid][row][1] = sq; }
        }
    __syncthreads();                                 // bar A: vt_bf + xdp ready

    // ---- kp/qp epilogues: xd inline from xdp, exp -> kp_s/qp_s ----
    const float scale = 0.08838834764831845f;        // 1/sqrt(128)
    #pragma unroll
    for (int m = 0; m < 2; m++)
        #pragma unroll
        for (int r = 0; r < 4; r++) {
            int row = m*16 + l4*4 + r;
            float xdk = 0.5f*(xdp[0][row][0]+xdp[1][row][0]+xdp[2][row][0]+xdp[3][row][0]);
            float xdq = 0.5f*(xdp[0][row][1]+xdp[1][row][1]+xdp[2][row][1]+xdp[3][row][1]);
            #pragma unroll
            for (int j = 4; j < 6; j++) {            // kp tiles
                int mcol = wid*16 + (j-4)*64 + l15;
                kp_s[row*128 + mcol] = f2bf(expf(acc[j][m][r] + bkq[mcol] - xdk) * scale);
            }
            #pragma unroll
            for (int j = 6; j < 8; j++) {            // qp tiles
                int mcol = wid*16 + (j-6)*64 + l15;
                qp_s[row*128 + mcol] = f2bf(expf(acc[j][m][r] + bkq[128 + mcol] - xdq) * scale);
            }
        }

    // ---- P4: vfrag write from vt_bf (overlaps with epilogue VALU above) ----
    {
        ushort* dst = vfrag_out + (size_t)blk*8192 + tid*32;
        #pragma unroll
        for (int t8 = 0; t8 < 4; t8++) {
            u16x8 pk8;
            #pragma unroll
            for (int j = 0; j < 8; j++) pk8[j] = vt_bf[(t8*8 + j)*256 + tid];
            *(u16x8*)&dst[t8*8] = pk8;
        }
    }
    __syncthreads();                                 // bar B: kp_s/qp_s ready

    // ---- P7: kp^T coalesced write ----
    if (tid < 128) {
        ushort* dst = kpT_out + ((size_t)(b*MF + tid))*TOK + t0;
        #pragma unroll
        for (int t8 = 0; t8 < 4; t8++) {
            u16x8 pk8;
            #pragma unroll
            for (int j = 0; j < 8; j++) pk8[j] = kp_s[(t8*8 + j)*128 + tid];
            *(u16x8*)&dst[t8*8] = pk8;
        }
    }
    // ---- P8: qp row-major coalesced write (2 KB/wave contiguous) ----
    {
        int tk = tid >> 3, seg = tid & 7;
        ushort* dst = qp_out + (size_t)(b*TOK + t0 + tk)*MF + seg*16;
        u16x8 a = *(const u16x8*)&qp_s[tk*128 + seg*16];
        u16x8 c = *(const u16x8*)&qp_s[tk*128 + seg*16 + 8];
        *(u16x8*)&dst[0] = a;
        *(u16x8*)&dst[8] = c;
    }
}

// ---------------- kernel 3: kptv partials via MFMA, 2 blocks/CU ------------------
// 512 blocks: b(2b) | ns(2b, 64-n slice) | kc(5b). Each wave: 16 n x 128 m.
__global__ __launch_bounds__(256) void k3_kptv_mfma(
    const ushort* __restrict__ vfrag, const ushort* __restrict__ kpT,
    float* __restrict__ part, float* __restrict__ ksump)
{
    int blk = blockIdx.x;
    int b = blk >> 7, ns = (blk >> 5) & 3, kc = blk & 31;
    const int tid = threadIdx.x;
    const int wid = tid >> 6;
    const int l15 = tid & 15, l4 = (tid >> 4) & 3;
    const int t0 = kc * 512;
    const int n0 = ns*64 + wid*16;
    const bool doks = (ns == 0) && (wid == 0);   // wave-uniform

    f32x4 acc[8];
    #pragma unroll
    for (int n = 0; n < 8; n++) { acc[n][0]=0.f; acc[n][1]=0.f; acc[n][2]=0.f; acc[n][3]=0.f; }
    float sks[8];
    #pragma unroll
    for (int n = 0; n < 8; n++) sks[n] = 0.f;

    #pragma unroll
    for (int ks = 0; ks < 16; ks++) {
        int k0 = t0 + ks*32 + l4*8;
        const ushort* vt = vfrag + (size_t)(b*512 + kc*16 + ks)*8192 + l4*8;
        bf16x8 a0 = *(const bf16x8*)&vt[(n0 + l15)*32];
        #pragma unroll
        for (int nt = 0; nt < 8; nt++) {
            bf16x8 bb = *(const bf16x8*)&kpT[((size_t)(b*MF + nt*16 + l15))*TOK + k0];
            if (doks) {
                #pragma unroll
                for (int j = 0; j < 8; j++) sks[nt] += bf2f((ushort)bb[j]);
            }
            acc[nt] = __builtin_amdgcn_mfma_f32_16x16x32_bf16(a0, bb, acc[nt], 0, 0, 0);
        }
    }
    if (doks) {
        #pragma unroll
        for (int nt = 0; nt < 8; nt++) {
            float s = sks[nt];
            s += __shfl_xor(s, 16);
            s += __shfl_xor(s, 32);
            if (l4 == 0 && tid < 64)
                ksump[(size_t)(b*32 + kc)*128 + nt*16 + l15] = s;
        }
    }
    #pragma unroll
    for (int nt = 0; nt < 8; nt++) {
        int n = n0 + l4*4;
        int m = nt*16 + l15;
        #pragma unroll
        for (int r = 0; r < 4; r++)
            part[(size_t)kc*131072 + (size_t)((b*EMB + n + r)*MF + m)] = acc[nt][r];
    }
}

// ---------------- kernel 3r: reduce partials -> kptv f32 (+ ksum finish) ---------
__global__ __launch_bounds__(256) void k3r_reduce(
    const float* __restrict__ part, const float* __restrict__ ksump,
    float* __restrict__ kptv, float* __restrict__ ksum)
{
    int blk = blockIdx.x;
    int e = blk*256 + threadIdx.x;
    float s = 0.f;
    #pragma unroll 8
    for (int kc = 0; kc < 32; kc++) s += part[(size_t)kc*131072 + e];
    kptv[e] = s;
    if (blk < 2) {
        int i = blk*256 + threadIdx.x;       // 512 = 4b x 128m
        int b = i >> 7, m = i & 127;
        float t = 0.f;
        #pragma unroll 8
        for (int kc = 0; kc < 32; kc++) t += ksump[(size_t)(b*32 + kc)*128 + m];
        ksum[i] = t;
    }
}

// ---------------- kernel 3c: C[b][m][n2] = kptv^T @ w_proj -> bf16 frag-major ----
__global__ __launch_bounds__(256) void k3c_combine(
    const float* __restrict__ kptv, const float* __restrict__ w_proj, ushort* __restrict__ C_bf)
{
    __shared__ float kp_s[256][8];
    int blk = blockIdx.x;            // 64: b(2b) | mg(4b)
    int b = blk >> 4, m0 = (blk & 15)*8;
    int tid = threadIdx.x;

    #pragma unroll
    for (int pass = 0; pass < 8; pass++) {
        int n1 = pass*32 + (tid >> 3);
        kp_s[n1][tid & 7] = kptv[b*32768 + n1*128 + m0 + (tid & 7)];
    }
    __syncthreads();

    float acc[8];
    #pragma unroll
    for (int j = 0; j < 8; j++) acc[j] = 0.f;
    for (int n1 = 0; n1 < 256; n1++) {
        float w = w_proj[n1*256 + tid];
        #pragma unroll
        for (int j = 0; j < 8; j++) acc[j] = fmaf(kp_s[n1][j], w, acc[j]);
    }
    u16x8 pk;
    #pragma unroll
    for (int j = 0; j < 8; j++) pk[j] = f2bf(acc[j]);
    int base = (((tid >> 4)*4 + (m0 >> 5))*4 + ((m0 >> 3) & 3))*128 + (tid & 15)*8;
    *(u16x8*)&C_bf[b*32768 + base] = pk;
}

// ---------------- kernel 4: 3 GEMMs, /D epilogue, bf16 channel-major out ---------
template<int K>
__device__ __forceinline__ void gemm32(const ushort* A_s, const ushort* __restrict__ B,
                                       f32x4 acc[2][4], int l15, int l4, int wid)
{
    __builtin_amdgcn_s_setprio(1);
    #pragma unroll
    for (int kc = 0; kc < (K >> 5); kc++) {
        const int ch = ((kc*4 + l4) ^ (l15 & 7)) << 3;
        bf16x8 a0 = *(const bf16x8*)&A_s[ l15      *256 + ch];
        bf16x8 a1 = *(const bf16x8*)&A_s[(16 + l15)*256 + ch];
        #pragma unroll
        for (int nt = 0; nt < 4; nt++) {
            int ntile = wid*4 + nt;
            bf16x8 bb = *(const bf16x8*)&B[(((ntile*(K >> 5) + kc)*4 + l4)*16 + l15)*8];
            acc[0][nt] = __builtin_amdgcn_mfma_f32_16x16x32_bf16(a0, bb, acc[0][nt], 0, 0, 0);
            acc[1][nt] = __builtin_amdgcn_mfma_f32_16x16x32_bf16(a1, bb, acc[1][nt], 0, 0, 0);
        }
    }
    __builtin_amdgcn_s_setprio(0);
}

__global__ __launch_bounds__(256, 4) void k4_attn_tail(
    const ushort* __restrict__ qp, const ushort* __restrict__ vfrag,
    const float* __restrict__ ksum, const ushort* __restrict__ C_bf,
    const ushort* __restrict__ wT2,
    const float* __restrict__ b_proj,
    const float* __restrict__ g2, const float* __restrict__ b2,
    const float* __restrict__ b_mlp1, const float* __restrict__ b_mlp2,
    ushort* __restrict__ img2b)
{
    __shared__ __align__(16) ushort A_s[16448];    // 32.9 KB
    __shared__ float D_s[32];
    __shared__ float redD[32][8];
    __shared__ float red1[4][32], red2[4][32];
    __shared__ float mu_s[32], iv_s[32];

    const int blk = blockIdx.x;                    // 2048
    const int b  = blk >> 9;
    const int t0 = (blk & 511) << 5;
    const int tid = threadIdx.x;
    const int wid = tid >> 6;
    const int lane = tid & 63;
    const int l15 = lane & 15, l4 = lane >> 4;

    // ---- prefetch v residual from [n][t] tile: 8 x 8B loads ----
    u16x4 vreg[8];
    {
        const ushort* vf = vfrag + (size_t)blk*8192 + l4*4;
        #pragma unroll
        for (int nt = 0; nt < 4; nt++)
            #pragma unroll
            for (int m = 0; m < 2; m++)
                vreg[nt*2 + m] = *(const u16x4*)&vf[(wid*64 + nt*16 + l15)*32 + m*16];
    }
    float bp[4];
    #pragma unroll
    for (int nt = 0; nt < 4; nt++) bp[nt] = b_proj[wid*64 + nt*16 + l15];

    // ---- stage qp (bf16 swizzled copy) + D = qp . ksum ----
    {
        int tk = tid >> 3, seg = tid & 7;
        const ushort* qrow = qp + (size_t)(b*TOK + t0 + tk)*MF + seg*16;
        u16x8 q0 = *(const u16x8*)&qrow[0];
        u16x8 q1 = *(const u16x8*)&qrow[8];
        const float* ks = ksum + b*MF + seg*16;
        float dd = 0.f;
        #pragma unroll
        for (int j = 0; j < 8; j++) {
            dd = fmaf(bf2f(q0[j]), ks[j],   dd);
            dd = fmaf(bf2f(q1[j]), ks[j+8], dd);
        }
        redD[tk][seg] = dd;
        int xr = tk & 7;
        *(u16x8*)&A_s[tk*256 + (((seg*2  ) ^ xr) << 3)] = q0;
        *(u16x8*)&A_s[tk*256 + (((seg*2+1) ^ xr) << 3)] = q1;
    }
    __syncthreads();
    if (tid < 32) {
        float s = 0.f;
        #pragma unroll
        for (int j = 0; j < 8; j++) s += redD[tid][j];
        D_s[tid] = s + 1e-8f;
    }

    f32x4 acc[2][4];
    #define ZACC() { _Pragma("unroll") for (int m_=0;m_<2;m_++) _Pragma("unroll") for (int n_=0;n_<4;n_++) { acc[m_][n_][0]=0.f;acc[m_][n_][1]=0.f;acc[m_][n_][2]=0.f;acc[m_][n_][3]=0.f; } }

    // ---- GEMMc: y2 = (qp @ C)/D + b_proj + v ----
    ZACC();
    gemm32<MF>(A_s, C_bf + (size_t)b*32768, acc, l15, l4, wid);
    __syncthreads();
    float y2[2][4][4];
    #pragma unroll
    for (int nt = 0; nt < 4; nt++) {
        #pragma unroll
        for (int m = 0; m < 2; m++)
            #pragma unroll
            for (int r = 0; r < 4; r++) {
                int row = m*16 + l4*4 + r;
                y2[m][nt][r] = acc[m][nt][r]/D_s[row] + bp[nt] + bf2f(vreg[nt*2 + m][r]);
            }
    }

    // ---- LayerNorm(y2) ----
    {
        #pragma unroll
        for (int m = 0; m < 2; m++)
            #pragma unroll
            for (int r = 0; r < 4; r++) {
                float s1 = 0.f, s2 = 0.f;
                #pragma unroll
                for (int nt = 0; nt < 4; nt++) {
                    float a = y2[m][nt][r];
                    s1 += a; s2 = fmaf(a, a, s2);
                }
                #pragma unroll
                for (int msk = 8; msk >= 1; msk >>= 1) {
                    s1 += __shfl_xor(s1, msk);
                    s2 += __shfl_xor(s2, msk);
                }
                if (l15 == 0) {
                    int row = m*16 + l4*4 + r;
                    red1[wid][row] = s1; red2[wid][row] = s2;
                }
            }
        __syncthreads();
        if (tid < 32) {
            float a = red1[0][tid] + red1[1][tid] + red1[2][tid] + red1[3][tid];
            float q = red2[0][tid] + red2[1][tid] + red2[2][tid] + red2[3][tid];
            float mu = a * (1.f/EMB);
            mu_s[tid] = mu;
            iv_s[tid] = rsqrtf(q*(1.f/EMB) - mu*mu + 1e-5f);
        }
        __syncthreads();
        #pragma unroll
        for (int nt = 0; nt < 4; nt++) {
            int col = wid*64 + nt*16 + l15;
            float gg = g2[col], bb = b2[col];
            #pragma unroll
            for (int m = 0; m < 2; m++)
                #pragma unroll
                for (int r = 0; r < 4; r++) {
                    int row = m*16 + l4*4 + r;
                    A_s[SWZ256(row, col)] = f2bf((y2[m][nt][r] - mu_s[row])*iv_s[row]*gg + bb);
                }
        }
    }
    __syncthreads();

    // ---- GEMM3: h1 = gelu(z @ w_mlp1 + b_mlp1) ----
    ZACC();
    gemm32<EMB>(A_s, wT2, acc, l15, l4, wid);
    __syncthreads();
    #pragma unroll
    for (int nt = 0; nt < 4; nt++) {
        int col = wid*64 + nt*16 + l15;
        float bm = b_mlp1[col];
        #pragma unroll
        for (int m = 0; m < 2; m++)
            #pragma unroll
            for (int r = 0; r < 4; r++) {
                int row = m*16 + l4*4 + r;
                float a = acc[m][nt][r] + bm;
                A_s[SWZ256(row, col)] = f2bf(0.5f*a*(1.f + erff(a*0.70710678118654752f)));
            }
    }
    __syncthreads();

    // ---- GEMM4: y3 = y2 + h1 @ w_mlp2 + b_mlp2 ----
    ZACC();
    gemm32<EMB>(A_s, wT2 + 65536, acc, l15, l4, wid);
    #pragma unroll
    for (int nt = 0; nt < 4; nt++) {
        int col = wid*64 + nt*16 + l15;
        float bm = b_mlp2[col];
        #pragma unroll
        for (int m = 0; m < 2; m++)
            #pragma unroll
            for (int r = 0; r < 4; r++)
                y2[m][nt][r] += acc[m][nt][r] + bm;
    }
    __syncthreads();

    // ---- output: stage f32 [32][257], write bf16 channel-major (8B/pass) ----
    float* A_f = (float*)A_s;
    #pragma unroll
    for (int nt = 0; nt < 4; nt++) {
        int col = wid*64 + nt*16 + l15;
        #pragma unroll
        for (int m = 0; m < 2; m++)
            #pragma unroll
            for (int r = 0; r < 4; r++)
                A_f[(m*16 + l4*4 + r)*257 + col] = y2[m][nt][r];
    }
    __syncthreads();
    {
        int tq = tid & 7, cb = tid >> 3;
        #pragma unroll
        for (int pass = 0; pass < 8; pass++) {
            int c = pass*32 + cb;
            u16x4 pk;
            #pragma unroll
            for (int j = 0; j < 4; j++) pk[j] = f2bf(A_f[(tq*4 + j)*257 + c]);
            *(u16x4*)&img2b[((size_t)(b*EMB + c))*TOK + t0 + tq*4] = pk;
        }
    }
}

// ---------------- kernel 6: bilinear upsample x2 (grid-stride, 8 chunks/block) ---
__global__ __launch_bounds__(256) void k6_upsample(const ushort* __restrict__ img2b, float* __restrict__ out)
{
    #pragma unroll
    for (int it = 0; it < 8; it++) {
        int idx = blockIdx.x*2048 + it*256 + threadIdx.x;
        int wq = idx & 63;
        int ho = (idx >> 6) & 255;
        int c  = (idx >> 14) & 255;
        int b  = idx >> 22;
        const float sc = 127.f/255.f;
        float fh = ho * sc; int h0 = (int)fh; if (h0 > 126) h0 = 126; float th = fh - h0;
        int wo = wq*4;
        int w0[4]; float tw[4];
        #pragma unroll
        for (int j = 0; j < 4; j++) {
            float fw = (wo + j) * sc;
            int w = (int)fw; if (w > 126) w = 126;
            w0[j] = w; tw[j] = fw - w;
        }
        int wsrt = w0[0] > 124 ? 124 : w0[0];
        const ushort* p = img2b + (((size_t)(b*EMB + c))*128 + h0)*128 + wsrt;
        float r0[4], r1[4];
        #pragma unroll
        for (int j = 0; j < 4; j++) { r0[j] = bf2f(p[j]); r1[j] = bf2f(p[128 + j]); }
        f32x4 o;
        #pragma unroll
        for (int j = 0; j < 4; j++) {
            int i = w0[j] - wsrt;                     // 0..2
            float a00 = (i == 0) ? r0[0] : ((i == 1) ? r0[1] : r0[2]);
            float a01 = (i == 0) ? r0[1] : ((i == 1) ? r0[2] : r0[3]);
            float a10 = (i == 0) ? r1[0] : ((i == 1) ? r1[1] : r1[2]);
            float a11 = (i == 0) ? r1[1] : ((i == 1) ? r1[2] : r1[3]);
            float top = fmaf(a01 - a00, tw[j], a00);
            float bot = fmaf(a11 - a10, tw[j], a10);
            o[j] = fmaf(bot - top, th, top);
        }
        *(f32x4*)&out[(size_t)idx*4] = o;
    }
}

extern "C" void kernel_launch(void* const* d_in, const int* in_sizes, int n_in,
                              void* d_out, int out_size, void* d_ws, size_t ws_size,
                              hipStream_t stream)
{
    const float* x      = (const float*)d_in[0];
    const float* g1     = (const float*)d_in[1];
    const float* b1     = (const float*)d_in[2];
    const float* w_kqv  = (const float*)d_in[3];
    const float* b_kqv  = (const float*)d_in[4];
    const float* w_prm  = (const float*)d_in[5];
    const float* w_proj = (const float*)d_in[6];
    const float* b_proj = (const float*)d_in[7];
    const float* g2     = (const float*)d_in[8];
    const float* b2     = (const float*)d_in[9];
    const float* w_mlp1 = (const float*)d_in[10];
    const float* b_mlp1 = (const float*)d_in[11];
    const float* w_mlp2 = (const float*)d_in[12];
    const float* b_mlp2 = (const float*)d_in[13];
    float* out = (float*)d_out;
    float* ws  = (float*)d_ws;

    ushort* vfrag    = (ushort*)(ws);              //  8,388,608 float slots [k1 -> k3,k4]
    ushort* qp_bf    = (ushort*)(ws + 8388608);    //  4,194,304 slots [k1 -> k4]
    ushort* kpT_bf   = (ushort*)(ws + 12582912);   //  4,194,304 slots [k1 -> k3]
    ushort* img2b    = (ushort*)(ws + 16777216);   //  8,388,608 slots [k4 -> k6]
    float*  ksum     = ws + 25165824;              //        512
    ushort* Wbig     = (ushort*)(ws + 25166336);   //     20,480 slots
    ushort* wT2      = (ushort*)(ws + 25186816);   //     65,536 slots
    float*  bkq      = ws + 25252352;              //        256
    float*  kptv_f32 = ws + 25252608;              //    131,072
    ushort* C_bf     = (ushort*)(ws + 25383680);   //     32,768 slots
    float*  ksump    = ws + 25416448;              //     16,384
    float*  part     = ws + 25432832;              //  4,194,304 slots (ends 29,627,136)

    hipLaunchKernelGGL(kprep, dim3(1153), dim3(256), 0, stream,
                       w_kqv, b_kqv, w_prm, w_mlp1, w_mlp2, Wbig, wT2, bkq);
    hipLaunchKernelGGL(k1_mfma, dim3(2048), dim3(256), 0, stream,
                       x, g1, b1, Wbig, b_kqv, bkq, vfrag, kpT_bf, qp_bf);
    hipLaunchKernelGGL(k3_kptv_mfma, dim3(512), dim3(256), 0, stream, vfrag, kpT_bf, part, ksump);
    hipLaunchKernelGGL(k3r_reduce, dim3(512), dim3(256), 0, stream, part, ksump, kptv_f32, ksum);
    hipLaunchKernelGGL(k3c_combine, dim3(64), dim3(256), 0, stream, kptv_f32, w_proj, C_bf);
    hipLaunchKernelGGL(k4_attn_tail, dim3(2048), dim3(256), 0, stream,
                       qp_bf, vfrag, ksum, C_bf, wT2, b_proj, g2, b2,
                       b_mlp1, b_mlp2, img2b);
    hipLaunchKernelGGL(k6_upsample, dim3(8192), dim3(256), 0, stream, img2b, out);
}

// Round 13
// 260.881 us; speedup vs baseline: 1.0417x; 1.0417x over previous
//
#include <hip/hip_runtime.h>
#include <math.h>

#define TOK   16384
#define DIM   48
#define EMB   256
#define MF    128
#define IMGsz 129

typedef __attribute__((ext_vector_type(8))) short    bf16x8;
typedef __attribute__((ext_vector_type(8))) unsigned short u16x8;
typedef __attribute__((ext_vector_type(4))) unsigned short u16x4;
typedef __attribute__((ext_vector_type(4))) float    f32x4;

__device__ __forceinline__ ushort f2bf(float f) {
    union { float f; unsigned u; } v; v.f = f;
    unsigned u = v.u;
    return (ushort)((u + 0x7fffu + ((u >> 16) & 1u)) >> 16);   // RNE
}
__device__ __forceinline__ float bf2f(ushort h) {
    union { unsigned u; float f; } v; v.u = ((unsigned)h) << 16; return v.f;
}

// swizzles: XOR 16B-chunk index with (row&7) -> conflict-free ds_read_b128
#define SWZ64(r,c)  ((r)*64  + (((((c)>>3) ^ ((r)&7)) & 7) << 3) + ((c)&7))
#define SWZ256(r,c) ((r)*256 + (((((c)>>3) ^ ((r)&7))) << 3) + ((c)&7))

// fragment-major dst index for B operands: lane(l4,l15) of (ntile,kc) is contiguous.
__device__ __forceinline__ int fragmajor(int n, int k, int KC) {
    return (((n >> 4)*KC + (k >> 5))*4 + ((k >> 3) & 3))*128 + (n & 15)*8 + (k & 7);
}

// ---------------- kprep: fused weight build (fragment-major bf16) ----------------
// Wbig[640 cols][64 k]: 0..255 Wv | 256..383 Wk@Pt | 384..511 Wq@Pt
//                      | 512..575 Gk_aug | 576..639 Gq_aug  (h[48]=1 trick)
__global__ __launch_bounds__(256) void kprep(
    const float* __restrict__ w_kqv, const float* __restrict__ b_kqv,
    const float* __restrict__ w_prm,
    const float* __restrict__ w_mlp1, const float* __restrict__ w_mlp2,
    ushort* __restrict__ Wbig, ushort* __restrict__ wT2, float* __restrict__ bkq)
{
    __shared__ float redp[64][4];
    int blk = blockIdx.x, tid = threadIdx.x;
    if (blk < 256) {                       // v weights
        if (tid < 64) {
            float v = (tid < DIM) ? w_kqv[tid*768 + 512 + blk] : 0.f;
            Wbig[fragmajor(blk, tid, 2)] = f2bf(v);
        }
    } else if (blk < 512) {                // fused kp/qp logit weights: Wk@P^T
        int isQ = (blk >= 384);
        int m = blk - (isQ ? 384 : 256);
        int d = tid & 63, part = tid >> 6;
        float s = 0.f;
        if (d < 48) {
            const float* wr = w_kqv + d*768 + (isQ ? 256 : 0);
            const float* pr = w_prm + m*256;
            for (int n = part*64; n < part*64 + 64; n++) s += wr[n]*pr[n];
        }
        redp[d][part] = s;
        __syncthreads();
        if (tid < 64)
            Wbig[fragmajor((isQ ? 384 : 256) + m, tid, 2)] =
                f2bf(redp[tid][0]+redp[tid][1]+redp[tid][2]+redp[tid][3]);
    } else if (blk < 640) {                // G_aug quadratic-form weights
        int isQ = (blk >= 576);
        int j = blk - (isQ ? 576 : 512);
        int i = tid & 63, part = tid >> 6;
        int off = isQ ? 256 : 0;
        float s = 0.f;
        for (int n = part*64; n < part*64 + 64; n++) {
            float wi = (i < 48) ? w_kqv[i*768 + off + n] : (i == 48 ? b_kqv[off + n] : 0.f);
            float wj = (j < 48) ? w_kqv[j*768 + off + n] : (j == 48 ? b_kqv[off + n] : 0.f);
            s += wi*wj;
        }
        redp[i][part] = s;
        __syncthreads();
        if (tid < 64)
            Wbig[fragmajor((isQ ? 576 : 512) + j, tid, 2)] =
                f2bf(redp[tid][0]+redp[tid][1]+redp[tid][2]+redp[tid][3]);
    } else if (blk < 1152) {               // mlp weights fragment-major
        int w = (blk >= 896);
        int n = blk - (w ? 896 : 640);
        const float* src = w ? w_mlp2 : w_mlp1;
        wT2[w*65536 + fragmajor(n, tid, 8)] = f2bf(src[tid*256 + n]);
    } else {                               // performer feature biases P@b
        float s = 0.f;
        int m = tid & 127, off = (tid >= 128) ? 256 : 0;
        for (int n = 0; n < 256; n++) s += w_prm[m*256 + n]*b_kqv[off + n];
        bkq[tid] = s;
    }
}

// ---------------- kernel 1: unfold+LN+fused single GEMM (N=640, K=64) ------------
// v written ONCE: vfrag[blk][n(256)][t_local(32)] bf16 — serves k3 (A-frags) + k4
__global__ __launch_bounds__(256, 3) void k1_mfma(
    const float* __restrict__ x, const float* __restrict__ g1, const float* __restrict__ b1,
    const ushort* __restrict__ Wbig, const float* __restrict__ b_kqv,
    const float* __restrict__ bkq,
    ushort* __restrict__ vfrag_out, ushort* __restrict__ kpT_out, ushort* __restrict__ qp_out)
{
    __shared__ __align__(16) ushort h_bf[32*64];     // 4 KB swizzled (aug col 48 = 1.0)
    __shared__ __align__(16) ushort vt_bf[32*256];   // 16 KB: v staging -> kp staging
    __shared__ float xdp[4][32][2];
    __shared__ float xd2[32][2];
    __shared__ float red1[32][8], red2[32][8];
    __shared__ float mu_s[32], iv_s[32];
    float* t_s = (float*)vt_bf;                      // [32][48] unfold overlay

    const int blk = blockIdx.x;                      // 2048
    const int b  = blk >> 9;
    const int t0 = (blk & 511) << 5;
    const int tid = threadIdx.x;
    const int wid = tid >> 6;
    const int l15 = tid & 15, l4 = (tid >> 4) & 3;

    // ---- unfold 32 tokens x 48 ----
    for (int e = tid; e < 32*DIM; e += 256) {
        int tok = e / DIM, j = e - tok*DIM;
        int t = t0 + tok;
        int lh = t >> 7, lw = t & 127;
        int c = j >> 4, kh = (j >> 2) & 3, kw = j & 3;
        int ih = lh + kh - 1, iw = lw + kw - 1;
        float val = 0.f;
        if (ih >= 0 && ih < IMGsz && iw >= 0 && iw < IMGsz)
            val = x[((b*3 + c)*IMGsz + ih)*IMGsz + iw];
        t_s[tok*DIM + j] = val;
    }
    __syncthreads();

    // ---- LayerNorm -> h_bf (swizzled), aug col 48 = 1.0 ----
    {
        int tg = tid >> 3, sl = tid & 7;
        const float* tr = &t_s[tg*DIM + sl*6];
        float s1 = 0.f, s2 = 0.f;
        #pragma unroll
        for (int j = 0; j < 6; j++) { float a = tr[j]; s1 += a; s2 = fmaf(a, a, s2); }
        red1[tg][sl] = s1; red2[tg][sl] = s2;
        __syncthreads();
        if (tid < 32) {
            float a = 0.f, q = 0.f;
            #pragma unroll
            for (int j = 0; j < 8; j++) { a += red1[tid][j]; q += red2[tid][j]; }
            float mu = a * (1.f/DIM);
            mu_s[tid] = mu;
            iv_s[tid] = rsqrtf(q*(1.f/DIM) - mu*mu + 1e-5f);
        }
        __syncthreads();
        float mu = mu_s[tg], iv = iv_s[tg];
        float hv[6];
        #pragma unroll
        for (int j = 0; j < 6; j++) hv[j] = (tr[j]-mu)*iv;
        #pragma unroll
        for (int j = 0; j < 6; j++) {
            int c = sl*6 + j;
            h_bf[SWZ64(tg, c)] = f2bf(hv[j]*g1[c] + b1[c]);
        }
        int c0 = 48 + sl*2;
        h_bf[SWZ64(tg, c0    )] = (sl == 0) ? (ushort)0x3F80 : (ushort)0;  // h[48]=1.0
        h_bf[SWZ64(tg, c0 + 1)] = 0;
    }
    __syncthreads();

    // ---- single GEMM: 40 tiles strided across 4 waves (10 tiles/wave) ----
    f32x4 acc[10][2];
    #pragma unroll
    for (int j = 0; j < 10; j++)
        #pragma unroll
        for (int m = 0; m < 2; m++) { acc[j][m][0]=0.f; acc[j][m][1]=0.f; acc[j][m][2]=0.f; acc[j][m][3]=0.f; }
    #pragma unroll
    for (int kc = 0; kc < 2; kc++) {
        int ch = ((kc*4 + l4) ^ (l15 & 7)) << 3;
        bf16x8 a0 = *(const bf16x8*)&h_bf[ l15      *64 + ch];
        bf16x8 a1 = *(const bf16x8*)&h_bf[(16 + l15)*64 + ch];
        #pragma unroll
        for (int j = 0; j < 10; j++) {
            int tile = wid + 4*j;
            bf16x8 bb = *(const bf16x8*)&Wbig[(((tile*2 + kc)*4 + l4)*16 + l15)*8];
            acc[j][0] = __builtin_amdgcn_mfma_f32_16x16x32_bf16(a0, bb, acc[j][0], 0, 0, 0);
            acc[j][1] = __builtin_amdgcn_mfma_f32_16x16x32_bf16(a1, bb, acc[j][1], 0, 0, 0);
        }
    }

    // ---- v epilogue (tiles 0..15): + bias -> vt_bf ----
    #pragma unroll
    for (int j = 0; j < 4; j++) {
        int col = (wid + 4*j)*16 + l15;
        float bias = b_kqv[512 + col];
        #pragma unroll
        for (int m = 0; m < 2; m++)
            #pragma unroll
            for (int r = 0; r < 4; r++) {
                int row = m*16 + l4*4 + r;
                vt_bf[row*256 + col] = f2bf(acc[j][m][r] + bias);
            }
    }
    // ---- u epilogue (tiles 32..39): xd = 0.5 * h G h^T partials ----
    #pragma unroll
    for (int m = 0; m < 2; m++)
        #pragma unroll
        for (int r = 0; r < 4; r++) {
            int row = m*16 + l4*4 + r;
            float hv = bf2f(h_bf[SWZ64(row, wid*16 + l15)]);
            float sk = acc[8][m][r]*hv, sq = acc[9][m][r]*hv;
            #pragma unroll
            for (int msk = 8; msk >= 1; msk >>= 1) {
                sk += __shfl_xor(sk, msk);
                sq += __shfl_xor(sq, msk);
            }
            if (l15 == 0) { xdp[wid][row][0] = sk; xdp[wid][row][1] = sq; }
        }
    __syncthreads();
    if (tid < 64) {
        int row = tid >> 1, ty = tid & 1;
        xd2[row][ty] = 0.5f*(xdp[0][row][ty] + xdp[1][row][ty] + xdp[2][row][ty] + xdp[3][row][ty]);
    }

    // ---- P4: single v write, [n][t] tile layout (64B/thread contiguous) ----
    {
        ushort* dst = vfrag_out + (size_t)blk*8192 + tid*32;
        #pragma unroll
        for (int t8 = 0; t8 < 4; t8++) {
            u16x8 pk8;
            #pragma unroll
            for (int j = 0; j < 8; j++) pk8[j] = vt_bf[(t8*8 + j)*256 + tid];
            *(u16x8*)&dst[t8*8] = pk8;
        }
    }
    __syncthreads();

    // ---- kp/qp epilogue (tiles 16..31): exp(logit + bias - xd) * scale ----
    const float scale = 0.08838834764831845f;        // 1/sqrt(128)
    #pragma unroll
    for (int j = 4; j < 6; j++) {                    // kp -> vt_bf staging
        int mcol = (wid + 4*j)*16 + l15 - 256;
        float bias = bkq[mcol];
        #pragma unroll
        for (int m = 0; m < 2; m++)
            #pragma unroll
            for (int r = 0; r < 4; r++) {
                int row = m*16 + l4*4 + r;
                vt_bf[row*256 + mcol] = f2bf(expf(acc[j][m][r] + bias - xd2[row][0]) * scale);
            }
    }
    #pragma unroll
    for (int j = 6; j < 8; j++) {                    // qp -> global row-major
        int mcol = (wid + 4*j)*16 + l15 - 384;
        float bias = bkq[128 + mcol];
        #pragma unroll
        for (int m = 0; m < 2; m++)
            #pragma unroll
            for (int r = 0; r < 4; r++) {
                int row = m*16 + l4*4 + r;
                qp_out[(size_t)(b*TOK + t0 + row)*MF + mcol] =
                    f2bf(expf(acc[j][m][r] + bias - xd2[row][1]) * scale);
            }
    }
    __syncthreads();

    // ---- P7: kp^T coalesced write ----
    if (tid < 128) {
        ushort* dst = kpT_out + ((size_t)(b*MF + tid))*TOK + t0;
        #pragma unroll
        for (int t8 = 0; t8 < 4; t8++) {
            u16x8 pk8;
            #pragma unroll
            for (int j = 0; j < 8; j++) pk8[j] = vt_bf[(t8*8 + j)*256 + tid];
            *(u16x8*)&dst[t8*8] = pk8;
        }
    }
}

// ---------------- kernel 2: ksum[b][m] = row-sum of kp^T ------------------------
__global__ __launch_bounds__(256) void k2_ksum(const ushort* __restrict__ kpT, float* __restrict__ ksum)
{
    __shared__ float red[4];
    int blk = blockIdx.x;
    int b = blk >> 7, m = blk & 127;
    int tid = threadIdx.x;
    const ushort* row = kpT + (size_t)(b*MF + m)*TOK;
    float s = 0.f;
    for (int i = tid; i < TOK/8; i += 256) {
        u16x8 v = *(const u16x8*)&row[i*8];
        #pragma unroll
        for (int j = 0; j < 8; j++) s += bf2f(v[j]);
    }
    #pragma unroll
    for (int msk = 32; msk >= 1; msk >>= 1) s += __shfl_xor(s, msk);
    if ((tid & 63) == 0) red[tid >> 6] = s;
    __syncthreads();
    if (tid == 0) ksum[b*MF + m] = red[0] + red[1] + red[2] + red[3];
}

// ---------------- kernel 3: kptv partials via MFMA (A from vfrag tiles) ----------
__global__ __launch_bounds__(256) void k3_kptv_mfma(
    const ushort* __restrict__ vfrag, const ushort* __restrict__ kpT, float* __restrict__ part)
{
    int blk = blockIdx.x;            // 256: b(2b) | ns(1b) | kc(5b)
    int b = blk >> 6, ns = (blk >> 5) & 1, kc = blk & 31;
    const int tid = threadIdx.x;
    const int wid = tid >> 6;
    const int l15 = tid & 15, l4 = (tid >> 4) & 3;
    const int t0 = kc * 512;
    const int n0 = ns*128 + wid*32;

    f32x4 acc[2][8];
    #pragma unroll
    for (int m = 0; m < 2; m++)
        #pragma unroll
        for (int n = 0; n < 8; n++) { acc[m][n][0]=0.f; acc[m][n][1]=0.f; acc[m][n][2]=0.f; acc[m][n][3]=0.f; }

    #pragma unroll
    for (int ks = 0; ks < 16; ks++) {
        int k0 = t0 + ks*32 + l4*8;
        // v A-frags from vfrag tile: block (b*512 + kc*16 + ks), [n][t_local]
        const ushort* vt = vfrag + (size_t)(b*512 + kc*16 + ks)*8192 + l4*8;
        bf16x8 a0 = *(const bf16x8*)&vt[(n0      + l15)*32];
        bf16x8 a1 = *(const bf16x8*)&vt[(n0 + 16 + l15)*32];
        #pragma unroll
        for (int nt = 0; nt < 8; nt++) {
            bf16x8 bb = *(const bf16x8*)&kpT[((size_t)(b*MF + nt*16 + l15))*TOK + k0];
            acc[0][nt] = __builtin_amdgcn_mfma_f32_16x16x32_bf16(a0, bb, acc[0][nt], 0, 0, 0);
            acc[1][nt] = __builtin_amdgcn_mfma_f32_16x16x32_bf16(a1, bb, acc[1][nt], 0, 0, 0);
        }
    }
    #pragma unroll
    for (int mt = 0; mt < 2; mt++)
        #pragma unroll
        for (int nt = 0; nt < 8; nt++) {
            int n = n0 + mt*16 + l4*4;
            int m = nt*16 + l15;
            #pragma unroll
            for (int r = 0; r < 4; r++)
                part[(size_t)kc*131072 + (size_t)((b*EMB + n + r)*MF + m)] = acc[mt][nt][r];
        }
}

// ---------------- kernel 3r: reduce partials -> kptv f32 -------------------------
__global__ __launch_bounds__(256) void k3r_reduce(const float* __restrict__ part, float* __restrict__ kptv)
{
    int e = blockIdx.x*256 + threadIdx.x;
    float s = 0.f;
    #pragma unroll 8
    for (int kc = 0; kc < 32; kc++) s += part[(size_t)kc*131072 + e];
    kptv[e] = s;
}

// ---------------- kernel 3c: C[b][m][n2] = kptv^T @ w_proj -> bf16 frag-major ----
__global__ __launch_bounds__(256) void k3c_combine(
    const float* __restrict__ kptv, const float* __restrict__ w_proj, ushort* __restrict__ C_bf)
{
    __shared__ float kp_s[256][8];
    int blk = blockIdx.x;            // 64: b(2b) | mg(4b)
    int b = blk >> 4, m0 = (blk & 15)*8;
    int tid = threadIdx.x;

    #pragma unroll
    for (int pass = 0; pass < 8; pass++) {
        int n1 = pass*32 + (tid >> 3);
        kp_s[n1][tid & 7] = kptv[b*32768 + n1*128 + m0 + (tid & 7)];
    }
    __syncthreads();

    float acc[8];
    #pragma unroll
    for (int j = 0; j < 8; j++) acc[j] = 0.f;
    for (int n1 = 0; n1 < 256; n1++) {
        float w = w_proj[n1*256 + tid];
        #pragma unroll
        for (int j = 0; j < 8; j++) acc[j] = fmaf(kp_s[n1][j], w, acc[j]);
    }
    u16x8 pk;
    #pragma unroll
    for (int j = 0; j < 8; j++) pk[j] = f2bf(acc[j]);
    int base = (((tid >> 4)*4 + (m0 >> 5))*4 + ((m0 >> 3) & 3))*128 + (tid & 15)*8;
    *(u16x8*)&C_bf[b*32768 + base] = pk;
}

// ---------------- kernel 4: 3 GEMMs, /D epilogue, bf16 channel-major out ---------
template<int K>
__device__ __forceinline__ void gemm32(const ushort* A_s, const ushort* __restrict__ B,
                                       f32x4 acc[2][4], int l15, int l4, int wid)
{
    __builtin_amdgcn_s_setprio(1);
    #pragma unroll
    for (int kc = 0; kc < (K >> 5); kc++) {
        const int ch = ((kc*4 + l4) ^ (l15 & 7)) << 3;
        bf16x8 a0 = *(const bf16x8*)&A_s[ l15      *256 + ch];
        bf16x8 a1 = *(const bf16x8*)&A_s[(16 + l15)*256 + ch];
        #pragma unroll
        for (int nt = 0; nt < 4; nt++) {
            int ntile = wid*4 + nt;
            bf16x8 bb = *(const bf16x8*)&B[(((ntile*(K >> 5) + kc)*4 + l4)*16 + l15)*8];
            acc[0][nt] = __builtin_amdgcn_mfma_f32_16x16x32_bf16(a0, bb, acc[0][nt], 0, 0, 0);
            acc[1][nt] = __builtin_amdgcn_mfma_f32_16x16x32_bf16(a1, bb, acc[1][nt], 0, 0, 0);
        }
    }
    __builtin_amdgcn_s_setprio(0);
}

__global__ __launch_bounds__(256, 4) void k4_attn_tail(
    const ushort* __restrict__ qp, const ushort* __restrict__ vfrag,
    const float* __restrict__ ksum, const ushort* __restrict__ C_bf,
    const ushort* __restrict__ wT2,
    const float* __restrict__ b_proj,
    const float* __restrict__ g2, const float* __restrict__ b2,
    const float* __restrict__ b_mlp1, const float* __restrict__ b_mlp2,
    ushort* __restrict__ img2b)
{
    __shared__ __align__(16) ushort A_s[16448];    // 32.9 KB
    __shared__ float D_s[32];
    __shared__ float redD[32][8];
    __shared__ float red1[4][32], red2[4][32];
    __shared__ float mu_s[32], iv_s[32];

    const int blk = blockIdx.x;                    // 2048
    const int b  = blk >> 9;
    const int t0 = (blk & 511) << 5;
    const int tid = threadIdx.x;
    const int wid = tid >> 6;
    const int lane = tid & 63;
    const int l15 = lane & 15, l4 = lane >> 4;

    // ---- prefetch v residual from [n][t] tile: 8 x 8B loads ----
    u16x4 vreg[8];
    {
        const ushort* vf = vfrag + (size_t)blk*8192 + l4*4;
        #pragma unroll
        for (int nt = 0; nt < 4; nt++)
            #pragma unroll
            for (int m = 0; m < 2; m++)
                vreg[nt*2 + m] = *(const u16x4*)&vf[(wid*64 + nt*16 + l15)*32 + m*16];
    }
    float bp[4];
    #pragma unroll
    for (int nt = 0; nt < 4; nt++) bp[nt] = b_proj[wid*64 + nt*16 + l15];

    // ---- stage qp (bf16 swizzled copy) + D = qp . ksum ----
    {
        int tk = tid >> 3, seg = tid & 7;
        const ushort* qrow = qp + (size_t)(b*TOK + t0 + tk)*MF + seg*16;
        u16x8 q0 = *(const u16x8*)&qrow[0];
        u16x8 q1 = *(const u16x8*)&qrow[8];
        const float* ks = ksum + b*MF + seg*16;
        float dd = 0.f;
        #pragma unroll
        for (int j = 0; j < 8; j++) {
            dd = fmaf(bf2f(q0[j]), ks[j],   dd);
            dd = fmaf(bf2f(q1[j]), ks[j+8], dd);
        }
        redD[tk][seg] = dd;
        int xr = tk & 7;
        *(u16x8*)&A_s[tk*256 + (((seg*2  ) ^ xr) << 3)] = q0;
        *(u16x8*)&A_s[tk*256 + (((seg*2+1) ^ xr) << 3)] = q1;
    }
    __syncthreads();
    if (tid < 32) {
        float s = 0.f;
        #pragma unroll
        for (int j = 0; j < 8; j++) s += redD[tid][j];
        D_s[tid] = s + 1e-8f;
    }

    f32x4 acc[2][4];
    #define ZACC() { _Pragma("unroll") for (int m_=0;m_<2;m_++) _Pragma("unroll") for (int n_=0;n_<4;n_++) { acc[m_][n_][0]=0.f;acc[m_][n_][1]=0.f;acc[m_][n_][2]=0.f;acc[m_][n_][3]=0.f; } }

    // ---- GEMMc: y2 = (qp @ C)/D + b_proj + v ----
    ZACC();
    gemm32<MF>(A_s, C_bf + (size_t)b*32768, acc, l15, l4, wid);
    __syncthreads();
    float y2[2][4][4];
    #pragma unroll
    for (int nt = 0; nt < 4; nt++) {
        #pragma unroll
        for (int m = 0; m < 2; m++)
            #pragma unroll
            for (int r = 0; r < 4; r++) {
                int row = m*16 + l4*4 + r;
                y2[m][nt][r] = acc[m][nt][r]/D_s[row] + bp[nt] + bf2f(vreg[nt*2 + m][r]);
            }
    }

    // ---- LayerNorm(y2) ----
    {
        #pragma unroll
        for (int m = 0; m < 2; m++)
            #pragma unroll
            for (int r = 0; r < 4; r++) {
                float s1 = 0.f, s2 = 0.f;
                #pragma unroll
                for (int nt = 0; nt < 4; nt++) {
                    float a = y2[m][nt][r];
                    s1 += a; s2 = fmaf(a, a, s2);
                }
                #pragma unroll
                for (int msk = 8; msk >= 1; msk >>= 1) {
                    s1 += __shfl_xor(s1, msk);
                    s2 += __shfl_xor(s2, msk);
                }
                if (l15 == 0) {
                    int row = m*16 + l4*4 + r;
                    red1[wid][row] = s1; red2[wid][row] = s2;
                }
            }
        __syncthreads();
        if (tid < 32) {
            float a = red1[0][tid] + red1[1][tid] + red1[2][tid] + red1[3][tid];
            float q = red2[0][tid] + red2[1][tid] + red2[2][tid] + red2[3][tid];
            float mu = a * (1.f/EMB);
            mu_s[tid] = mu;
            iv_s[tid] = rsqrtf(q*(1.f/EMB) - mu*mu + 1e-5f);
        }
        __syncthreads();
        #pragma unroll
        for (int nt = 0; nt < 4; nt++) {
            int col = wid*64 + nt*16 + l15;
            float gg = g2[col], bb = b2[col];
            #pragma unroll
            for (int m = 0; m < 2; m++)
                #pragma unroll
                for (int r = 0; r < 4; r++) {
                    int row = m*16 + l4*4 + r;
                    A_s[SWZ256(row, col)] = f2bf((y2[m][nt][r] - mu_s[row])*iv_s[row]*gg + bb);
                }
        }
    }
    __syncthreads();

    // ---- GEMM3: h1 = gelu(z @ w_mlp1 + b_mlp1) ----
    ZACC();
    gemm32<EMB>(A_s, wT2, acc, l15, l4, wid);
    __syncthreads();
    #pragma unroll
    for (int nt = 0; nt < 4; nt++) {
        int col = wid*64 + nt*16 + l15;
        float bm = b_mlp1[col];
        #pragma unroll
        for (int m = 0; m < 2; m++)
            #pragma unroll
            for (int r = 0; r < 4; r++) {
                int row = m*16 + l4*4 + r;
                float a = acc[m][nt][r] + bm;
                A_s[SWZ256(row, col)] = f2bf(0.5f*a*(1.f + erff(a*0.70710678118654752f)));
            }
    }
    __syncthreads();

    // ---- GEMM4: y3 = y2 + h1 @ w_mlp2 + b_mlp2 ----
    ZACC();
    gemm32<EMB>(A_s, wT2 + 65536, acc, l15, l4, wid);
    #pragma unroll
    for (int nt = 0; nt < 4; nt++) {
        int col = wid*64 + nt*16 + l15;
        float bm = b_mlp2[col];
        #pragma unroll
        for (int m = 0; m < 2; m++)
            #pragma unroll
            for (int r = 0; r < 4; r++)
                y2[m][nt][r] += acc[m][nt][r] + bm;
    }
    __syncthreads();

    // ---- output: stage f32 [32][257], write bf16 channel-major (8B/pass) ----
    float* A_f = (float*)A_s;
    #pragma unroll
    for (int nt = 0; nt < 4; nt++) {
        int col = wid*64 + nt*16 + l15;
        #pragma unroll
        for (int m = 0; m < 2; m++)
            #pragma unroll
            for (int r = 0; r < 4; r++)
                A_f[(m*16 + l4*4 + r)*257 + col] = y2[m][nt][r];
    }
    __syncthreads();
    {
        int tq = tid & 7, cb = tid >> 3;
        #pragma unroll
        for (int pass = 0; pass < 8; pass++) {
            int c = pass*32 + cb;
            u16x4 pk;
            #pragma unroll
            for (int j = 0; j < 4; j++) pk[j] = f2bf(A_f[(tq*4 + j)*257 + c]);
            *(u16x4*)&img2b[((size_t)(b*EMB + c))*TOK + t0 + tq*4] = pk;
        }
    }
}

// ---------------- kernel 6: bilinear upsample x2 from bf16 (4 outputs/thread) ----
__global__ __launch_bounds__(256) void k6_upsample(const ushort* __restrict__ img2b, float* __restrict__ out)
{
    int idx = blockIdx.x*256 + threadIdx.x;
    int wq = idx & 63;
    int ho = (idx >> 6) & 255;
    int c  = (idx >> 14) & 255;
    int b  = idx >> 22;
    const float sc = 127.f/255.f;
    float fh = ho * sc; int h0 = (int)fh; if (h0 > 126) h0 = 126; float th = fh - h0;
    int wo = wq*4;
    int w0[4]; float tw[4];
    #pragma unroll
    for (int j = 0; j < 4; j++) {
        float fw = (wo + j) * sc;
        int w = (int)fw; if (w > 126) w = 126;
        w0[j] = w; tw[j] = fw - w;
    }
    int wsrt = w0[0] > 124 ? 124 : w0[0];
    const ushort* p = img2b + (((size_t)(b*EMB + c))*128 + h0)*128 + wsrt;
    float r0[4], r1[4];
    #pragma unroll
    for (int j = 0; j < 4; j++) { r0[j] = bf2f(p[j]); r1[j] = bf2f(p[128 + j]); }
    f32x4 o;
    #pragma unroll
    for (int j = 0; j < 4; j++) {
        int i = w0[j] - wsrt;                     // 0..2
        float a00 = (i == 0) ? r0[0] : ((i == 1) ? r0[1] : r0[2]);
        float a01 = (i == 0) ? r0[1] : ((i == 1) ? r0[2] : r0[3]);
        float a10 = (i == 0) ? r1[0] : ((i == 1) ? r1[1] : r1[2]);
        float a11 = (i == 0) ? r1[1] : ((i == 1) ? r1[2] : r1[3]);
        float top = fmaf(a01 - a00, tw[j], a00);
        float bot = fmaf(a11 - a10, tw[j], a10);
        o[j] = fmaf(bot - top, th, top);
    }
    *(f32x4*)&out[(size_t)idx*4] = o;
}

extern "C" void kernel_launch(void* const* d_in, const int* in_sizes, int n_in,
                              void* d_out, int out_size, void* d_ws, size_t ws_size,
                              hipStream_t stream)
{
    const float* x      = (const float*)d_in[0];
    const float* g1     = (const float*)d_in[1];
    const float* b1     = (const float*)d_in[2];
    const float* w_kqv  = (const float*)d_in[3];
    const float* b_kqv  = (const float*)d_in[4];
    const float* w_prm  = (const float*)d_in[5];
    const float* w_proj = (const float*)d_in[6];
    const float* b_proj = (const float*)d_in[7];
    const float* g2     = (const float*)d_in[8];
    const float* b2     = (const float*)d_in[9];
    const float* w_mlp1 = (const float*)d_in[10];
    const float* b_mlp1 = (const float*)d_in[11];
    const float* w_mlp2 = (const float*)d_in[12];
    const float* b_mlp2 = (const float*)d_in[13];
    float* out = (float*)d_out;
    float* ws  = (float*)d_ws;

    ushort* vfrag    = (ushort*)(ws);              //  8,388,608 float slots [k1 -> k3,k4]
    ushort* qp_bf    = (ushort*)(ws + 8388608);    //  4,194,304 slots [k1 -> k4]
    ushort* kpT_bf   = (ushort*)(ws + 12582912);   //  4,194,304 slots [k1 -> k2,k3]
    ushort* img2b    = (ushort*)(ws + 16777216);   //  8,388,608 slots [k4 -> k6]
    float*  ksum     = ws + 25165824;              //        512
    ushort* Wbig     = (ushort*)(ws + 25166336);   //     20,480 slots
    ushort* wT2      = (ushort*)(ws + 25186816);   //     65,536 slots
    float*  bkq      = ws + 25252352;              //        256
    float*  kptv_f32 = ws + 25252608;              //    131,072
    ushort* C_bf     = (ushort*)(ws + 25383680);   //     32,768 slots
    float*  part     = ws + 25416448;              //  4,194,304 slots (ends 29,610,752 = 118 MB)

    hipLaunchKernelGGL(kprep, dim3(1153), dim3(256), 0, stream,
                       w_kqv, b_kqv, w_prm, w_mlp1, w_mlp2, Wbig, wT2, bkq);
    hipLaunchKernelGGL(k1_mfma, dim3(2048), dim3(256), 0, stream,
                       x, g1, b1, Wbig, b_kqv, bkq, vfrag, kpT_bf, qp_bf);
    hipLaunchKernelGGL(k2_ksum, dim3(512), dim3(256), 0, stream, kpT_bf, ksum);
    hipLaunchKernelGGL(k3_kptv_mfma, dim3(256), dim3(256), 0, stream, vfrag, kpT_bf, part);
    hipLaunchKernelGGL(k3r_reduce, dim3(512), dim3(256), 0, stream, part, kptv_f32);
    hipLaunchKernelGGL(k3c_combine, dim3(64), dim3(256), 0, stream, kptv_f32, w_proj, C_bf);
    hipLaunchKernelGGL(k4_attn_tail, dim3(2048), dim3(256), 0, stream,
                       qp_bf, vfrag, ksum, C_bf, wT2, b_proj, g2, b2,
                       b_mlp1, b_mlp2, img2b);
    hipLaunchKernelGGL(k6_upsample, dim3(65536), dim3(256), 0, stream, img2b, out);
}